// Round 1
// 221.830 us; speedup vs baseline: 1.2187x; 1.2187x over previous
//
#include <hip/hip_runtime.h>
#include <hip/hip_fp16.h>

#define EMB_D 64
#define SB 1024     // scan block size
#define SPAN 128    // nodes per group (pow2: group = dst>>7, local = dst&127)
#define MAXG 1024   // max groups supported by LDS arrays
#define NCHUNK 256  // edge chunks for the partition pass

// ===========================================================================
// Tier A2: ZERO global atomics (two-level LDS counting sort).
//   A1: fused fp16 cast + per-chunk group histogram (LDS atomics)
//   scan: 3-phase over [G][NCHUNK] matrix -> per-(chunk,group) bases
//   A3: scatter (src|w15, dstlocal) into group-contiguous streams (LDS cursors)
//   B : per-group block: LDS node hist -> offsets[] + exact CSR placement
//   P3: gatherS (quarter-wave, 2-deep pipeline, fused L2 norm) -- unchanged
// Tier A: previous one-global-atomic-pass pipeline (proven 270 us).
// Tier B: R11 pipeline (proven 308 us). Tier C: atomic scatter.
// ===========================================================================

__device__ __forceinline__ float h15_to_float(unsigned int bits) {
    return __half2float(__ushort_as_half((unsigned short)bits));
}

#define CAST_BLOCKS 256

// --- A1: fused cast + chunked group histogram (no global atomics) ---------
__global__ void a1_cast_hist(const float2* __restrict__ embin,
                             __half2* __restrict__ emb16, int n2,
                             const int* __restrict__ dst,
                             int* __restrict__ cntT,   // [G][NCHUNK]
                             int E, int G, int chunk) {
    if (blockIdx.x < CAST_BLOCKS) {
        int i = blockIdx.x * blockDim.x + threadIdx.x;
        int st = CAST_BLOCKS * blockDim.x;
        for (; i < n2; i += st)
            emb16[i] = __float22half2_rn(embin[i]);
    } else {
        __shared__ int bins[MAXG];
        int hb = blockIdx.x - CAST_BLOCKS;
        for (int g = threadIdx.x; g < G; g += blockDim.x) bins[g] = 0;
        __syncthreads();
        int beg = hb * chunk;
        int end = min(beg + chunk, E);
        for (int i = beg + threadIdx.x; i < end; i += blockDim.x)
            atomicAdd(&bins[dst[i] >> 7], 1);
        __syncthreads();
        for (int g = threadIdx.x; g < G; g += blockDim.x)
            cntT[g * NCHUNK + hb] = bins[g];
    }
}

// --- generic 3-phase exclusive scan ---------------------------------------
__global__ void scan_reduceB(const int* __restrict__ counts,
                             int* __restrict__ partial, int M) {
    __shared__ int wsum[16];
    const int tid = threadIdx.x, lane = tid & 63, wid = tid >> 6;
    int i = blockIdx.x * SB + tid;
    int v = (i < M) ? counts[i] : 0;
    #pragma unroll
    for (int off = 32; off > 0; off >>= 1)
        v += __shfl_xor(v, off, 64);
    if (lane == 0) wsum[wid] = v;
    __syncthreads();
    if (tid == 0) {
        int s = 0;
        #pragma unroll
        for (int k = 0; k < 16; ++k) s += wsum[k];
        partial[blockIdx.x] = s;
    }
}

__global__ void scan_partials(const int* __restrict__ partial,
                              int* __restrict__ blockoff,
                              int* __restrict__ offsets, int numB, int M) {
    __shared__ int wsum[16];
    __shared__ int wpre[16];
    const int tid = threadIdx.x, lane = tid & 63, wid = tid >> 6;
    int v = (tid < numB) ? partial[tid] : 0;
    int x = v;
    #pragma unroll
    for (int off = 1; off < 64; off <<= 1) {
        int t = __shfl_up(x, off, 64);
        if (lane >= off) x += t;
    }
    if (lane == 63) wsum[wid] = x;
    __syncthreads();
    if (wid == 0) {
        int s = (lane < 16) ? wsum[lane] : 0;
        #pragma unroll
        for (int off = 1; off < 16; off <<= 1) {
            int t = __shfl_up(s, off, 64);
            if (lane >= off) s += t;
        }
        if (lane < 16) wpre[lane] = s;
    }
    __syncthreads();
    int excl = ((wid > 0) ? wpre[wid - 1] : 0) + (x - v);
    if (tid < numB) blockoff[tid] = excl;
    if (tid == 0) offsets[M] = wpre[15];   // grand total = E
}

__global__ void scan_applyB(const int* __restrict__ counts,
                            const int* __restrict__ blockoff,
                            int* __restrict__ offsets, int M) {
    __shared__ int wsum[16];
    __shared__ int wpre[16];
    const int tid = threadIdx.x, lane = tid & 63, wid = tid >> 6;
    int i = blockIdx.x * SB + tid;
    int v = (i < M) ? counts[i] : 0;
    int x = v;
    #pragma unroll
    for (int off = 1; off < 64; off <<= 1) {
        int t = __shfl_up(x, off, 64);
        if (lane >= off) x += t;
    }
    if (lane == 63) wsum[wid] = x;
    __syncthreads();
    if (wid == 0) {
        int s = (lane < 16) ? wsum[lane] : 0;
        #pragma unroll
        for (int off = 1; off < 16; off <<= 1) {
            int t = __shfl_up(s, off, 64);
            if (lane >= off) s += t;
        }
        if (lane < 16) wpre[lane] = s;
    }
    __syncthreads();
    int excl = blockoff[blockIdx.x] + ((wid > 0) ? wpre[wid - 1] : 0) + (x - v);
    if (i < M) offsets[i] = excl;
}

// --- A3: scatter edges into group-contiguous streams (LDS cursors only) ---
__global__ void partition_scatter(const int* __restrict__ src,
                                  const int* __restrict__ dst,
                                  const float* __restrict__ w,
                                  const int* __restrict__ scanT,   // [G*NCHUNK+1]
                                  unsigned int* __restrict__ pkS,  // [E]
                                  unsigned char* __restrict__ dlS, // [E]
                                  int E, int G, int chunk) {
    __shared__ int cur[MAXG];
    int b = blockIdx.x;
    for (int g = threadIdx.x; g < G; g += blockDim.x)
        cur[g] = scanT[g * NCHUNK + b];
    __syncthreads();
    int beg = b * chunk;
    int end = min(beg + chunk, E);
    for (int i = beg + threadIdx.x; i < end; i += blockDim.x) {
        int d = dst[i];
        unsigned int wb = __half_as_ushort(__float2half_rn(w[i]));
        unsigned int pk = ((unsigned int)src[i] << 15) | (wb & 0x7FFFu);
        int pos = atomicAdd(&cur[d >> 7], 1);
        pkS[pos] = pk;
        dlS[pos] = (unsigned char)(d & (SPAN - 1));
    }
}

// --- B: per-group CSR finalize: offsets[] + exact slot placement ----------
__global__ void group_csr(const unsigned int* __restrict__ pkS,
                          const unsigned char* __restrict__ dlS,
                          const int* __restrict__ scanT,
                          unsigned int* __restrict__ packed,
                          int* __restrict__ offsets, int N, int E) {
    __shared__ int hcnt[SPAN];
    __shared__ int cur[SPAN];
    __shared__ int wtot[4];
    int g = blockIdx.x;
    int tid = threadIdx.x;
    int base = scanT[g * NCHUNK];
    int endE = scanT[(g + 1) * NCHUNK];   // g == G-1 -> scanT[G*NCHUNK] = E
    if (tid < SPAN) hcnt[tid] = 0;
    __syncthreads();
    for (int i = base + tid; i < endE; i += blockDim.x)
        atomicAdd(&hcnt[dlS[i]], 1);
    __syncthreads();
    // exclusive scan of 128 counters across waves 0-1
    int v = (tid < SPAN) ? hcnt[tid] : 0;
    int lane = tid & 63, wv = tid >> 6;
    int x = v;
    #pragma unroll
    for (int off = 1; off < 64; off <<= 1) {
        int t = __shfl_up(x, off, 64);
        if (lane >= off) x += t;
    }
    if (lane == 63) wtot[wv] = x;
    __syncthreads();
    if (tid < SPAN) {
        int excl = x - v + ((wv == 1) ? wtot[0] : 0);
        cur[tid] = base + excl;
        int node = g * SPAN + tid;
        if (node < N) offsets[node] = base + excl;
    }
    if (g == 0 && tid == 0) offsets[N] = E;
    __syncthreads();
    for (int i = base + tid; i < endE; i += blockDim.x) {
        unsigned int pk = pkS[i];
        int slot = atomicAdd(&cur[dlS[i]], 1);
        packed[slot] = pk;
    }
}

// --- P1 (old Tier A): fused cast + histogram-with-ranks -------------------
__global__ void p1_cast_hist_ranks(const float2* __restrict__ embin,
                                   __half2* __restrict__ emb16, int n2,
                                   const int* __restrict__ dst,
                                   int* __restrict__ counts,
                                   unsigned short* __restrict__ ranks,
                                   int E) {
    if (blockIdx.x < CAST_BLOCKS) {
        int i = blockIdx.x * blockDim.x + threadIdx.x;
        int st = CAST_BLOCKS * blockDim.x;
        for (; i < n2; i += st)
            emb16[i] = __float22half2_rn(embin[i]);
    } else {
        int i = (blockIdx.x - CAST_BLOCKS) * blockDim.x + threadIdx.x;
        int st = (gridDim.x - CAST_BLOCKS) * blockDim.x;
        for (; i < E; i += st)
            ranks[i] = (unsigned short)atomicAdd(&counts[dst[i]], 1);
    }
}

// --- P2 (old Tier A): atomic-free packed bucket ---------------------------
__global__ void bucketR_kernel(const int* __restrict__ src,
                               const int* __restrict__ dst,
                               const float* __restrict__ w,
                               const unsigned short* __restrict__ ranks,
                               const int* __restrict__ offsets,
                               unsigned int* __restrict__ packed,
                               int E, int span, int N) {
    int g = blockIdx.x & 7;
    int b = blockIdx.x >> 3;
    int lo = g * span;
    int hi = min(lo + span, N);
    int stride = (gridDim.x >> 3) * blockDim.x;
    for (int i = b * blockDim.x + threadIdx.x; i < E; i += stride) {
        int v = dst[i];
        if (v >= lo && v < hi) {
            unsigned int wb = __half_as_ushort(__float2half_rn(w[i]));
            packed[offsets[v] + (int)ranks[i]] =
                ((unsigned int)src[i] << 15) | (wb & 0x7FFFu);
        }
    }
}

// --- P3: fp16 gather, quarter-wave per edge, 2-deep pipeline --------------
__global__ __launch_bounds__(256) void gatherS_kernel(
        const uint2* __restrict__ emb16,       // row v = 16 x uint2 (128 B)
        const int* __restrict__ offsets,       // [N+1]
        const unsigned int* __restrict__ packed,
        float* __restrict__ out, int N) {
    int node = blockIdx.x * 4 + (threadIdx.x >> 6);
    int lane = threadIdx.x & 63;
    if (node >= N) return;
    int q  = lane >> 4;
    int ql = lane & 15;

    int beg = offsets[node];
    int end = offsets[node + 1];

    float a0 = 0.f, a1 = 0.f, a2 = 0.f, a3 = 0.f;

    int idx0 = beg + q;
    unsigned int pk0 = (idx0 < end) ? packed[idx0] : 0u;
    uint2 r0 = emb16[(size_t)(pk0 >> 15) * 16 + ql];

    for (int j = beg; j < end; j += 4) {
        int idx1 = idx0 + 4;
        unsigned int pk1 = (idx1 < end) ? packed[idx1] : 0u;
        uint2 r1 = emb16[(size_t)(pk1 >> 15) * 16 + ql];  // next in flight

        float wt = h15_to_float(pk0 & 0x7FFFu);
        float2 x01 = __half22float2(*reinterpret_cast<__half2*>(&r0.x));
        float2 x23 = __half22float2(*reinterpret_cast<__half2*>(&r0.y));
        a0 = fmaf(x01.x, wt, a0);
        a1 = fmaf(x01.y, wt, a1);
        a2 = fmaf(x23.x, wt, a2);
        a3 = fmaf(x23.y, wt, a3);

        pk0 = pk1; r0 = r1; idx0 = idx1;
    }

    a0 += __shfl_xor(a0, 16, 64); a0 += __shfl_xor(a0, 32, 64);
    a1 += __shfl_xor(a1, 16, 64); a1 += __shfl_xor(a1, 32, 64);
    a2 += __shfl_xor(a2, 16, 64); a2 += __shfl_xor(a2, 32, 64);
    a3 += __shfl_xor(a3, 16, 64); a3 += __shfl_xor(a3, 32, 64);

    float ss = a0 * a0 + a1 * a1 + a2 * a2 + a3 * a3;
    #pragma unroll
    for (int off = 8; off > 0; off >>= 1)
        ss += __shfl_xor(ss, off, 64);
    float scale = 1.0f / fmaxf(sqrtf(ss), 1e-12f);

    if (q == 0) {
        float4 o = make_float4(a0 * scale, a1 * scale, a2 * scale, a3 * scale);
        reinterpret_cast<float4*>(out + (size_t)node * EMB_D)[ql] = o;
    }
}

// ===========================================================================
// Tier B: R11 pipeline (proven 308 us).
// ===========================================================================
__global__ void fused_cast_hist(const float2* __restrict__ embin,
                                __half2* __restrict__ emb16, int n2,
                                const int* __restrict__ dst,
                                int* __restrict__ counts8, int E, int N) {
    if (blockIdx.x < CAST_BLOCKS) {
        int i = blockIdx.x * blockDim.x + threadIdx.x;
        int st = CAST_BLOCKS * blockDim.x;
        for (; i < n2; i += st)
            emb16[i] = __float22half2_rn(embin[i]);
    } else {
        int* mycounts = counts8 + (size_t)(blockIdx.x & 7) * N;
        int i = (blockIdx.x - CAST_BLOCKS) * blockDim.x + threadIdx.x;
        int st = (gridDim.x - CAST_BLOCKS) * blockDim.x;
        for (; i < E; i += st)
            atomicAdd(&mycounts[dst[i]], 1);
    }
}

__device__ __forceinline__ int fold8(const int* counts8, int i, int N) {
    int v = 0;
    #pragma unroll
    for (int g = 0; g < 8; ++g) v += counts8[(size_t)g * N + i];
    return v;
}

__global__ void scan_reduceF(const int* __restrict__ counts8,
                             int* __restrict__ partial, int N) {
    __shared__ int wsum[16];
    const int tid = threadIdx.x, lane = tid & 63, wid = tid >> 6;
    int i = blockIdx.x * SB + tid;
    int v = (i < N) ? fold8(counts8, i, N) : 0;
    #pragma unroll
    for (int off = 32; off > 0; off >>= 1)
        v += __shfl_xor(v, off, 64);
    if (lane == 0) wsum[wid] = v;
    __syncthreads();
    if (tid == 0) {
        int s = 0;
        #pragma unroll
        for (int k = 0; k < 16; ++k) s += wsum[k];
        partial[blockIdx.x] = s;
    }
}

__global__ void scan_applyF(const int* __restrict__ counts8,
                            const int* __restrict__ blockoff,
                            int* __restrict__ offsets,
                            int* __restrict__ cursors, int N) {
    __shared__ int wsum[16];
    __shared__ int wpre[16];
    const int tid = threadIdx.x, lane = tid & 63, wid = tid >> 6;
    int i = blockIdx.x * SB + tid;
    int v = (i < N) ? fold8(counts8, i, N) : 0;
    int x = v;
    #pragma unroll
    for (int off = 1; off < 64; off <<= 1) {
        int t = __shfl_up(x, off, 64);
        if (lane >= off) x += t;
    }
    if (lane == 63) wsum[wid] = x;
    __syncthreads();
    if (wid == 0) {
        int s = (lane < 16) ? wsum[lane] : 0;
        #pragma unroll
        for (int off = 1; off < 16; off <<= 1) {
            int t = __shfl_up(s, off, 64);
            if (lane >= off) s += t;
        }
        if (lane < 16) wpre[lane] = s;
    }
    __syncthreads();
    int excl = blockoff[blockIdx.x] + ((wid > 0) ? wpre[wid - 1] : 0) + (x - v);
    if (i < N) { offsets[i] = excl; cursors[i] = excl; }
}

__global__ void bucketS_kernel(const int* __restrict__ src,
                               const int* __restrict__ dst,
                               const float* __restrict__ w,
                               int* __restrict__ cursors,
                               unsigned int* __restrict__ packed,
                               int E, int span, int N) {
    int g = blockIdx.x & 7;
    int b = blockIdx.x >> 3;
    int lo = g * span;
    int hi = min(lo + span, N);
    int stride = (gridDim.x >> 3) * blockDim.x;
    for (int i = b * blockDim.x + threadIdx.x; i < E; i += stride) {
        int v = dst[i];
        if (v >= lo && v < hi) {
            int slot = atomicAdd(&cursors[v], 1);
            unsigned int wb = __half_as_ushort(__float2half_rn(w[i]));
            packed[slot] = ((unsigned int)src[i] << 15) | (wb & 0x7FFFu);
        }
    }
}

// ===========================================================================
// Tier C: atomic scatter fallback.
// ===========================================================================
__global__ void lightgcn_scatter(const float* __restrict__ emb,
                                 const float* __restrict__ w,
                                 const int* __restrict__ src,
                                 const int* __restrict__ dst,
                                 float* __restrict__ h, int E) {
    long long t = (long long)blockIdx.x * blockDim.x + threadIdx.x;
    int e = (int)(t >> 4);
    int d = (int)(t & 15) << 2;
    if (e >= E) return;
    int s = src[e]; int v = dst[e]; float wt = w[e];
    const float4 m = *reinterpret_cast<const float4*>(emb + (size_t)s * EMB_D + d);
    float* o = h + (size_t)v * EMB_D + d;
    unsafeAtomicAdd(o + 0, m.x * wt);
    unsafeAtomicAdd(o + 1, m.y * wt);
    unsafeAtomicAdd(o + 2, m.z * wt);
    unsafeAtomicAdd(o + 3, m.w * wt);
}

__global__ void lightgcn_normalize(float* __restrict__ h, int N) {
    int row = blockIdx.x * (blockDim.x >> 6) + (threadIdx.x >> 6);
    int lane = threadIdx.x & 63;
    if (row >= N) return;
    float x = h[(size_t)row * EMB_D + lane];
    float ss = x * x;
    #pragma unroll
    for (int off = 32; off > 0; off >>= 1)
        ss += __shfl_xor(ss, off, 64);
    h[(size_t)row * EMB_D + lane] = x / fmaxf(sqrtf(ss), 1e-12f);
}

extern "C" void kernel_launch(void* const* d_in, const int* in_sizes, int n_in,
                              void* d_out, int out_size, void* d_ws, size_t ws_size,
                              hipStream_t stream) {
    const float* emb = (const float*)d_in[0];   // [N, 64] fp32
    const float* w   = (const float*)d_in[1];   // [E] fp32
    const int*   src = (const int*)d_in[2];     // [E] int32
    const int*   dst = (const int*)d_in[3];     // [E] int32
    float* out = (float*)d_out;

    const int N = in_sizes[0] / EMB_D;
    const int E = in_sizes[1];
    const int block = 256;
    const int numB = (N + SB - 1) / SB;

    // ---- Tier A2 workspace: cntT[G*NCHUNK] | scanT[G*NCHUNK+1] | partial |
    //      blockoff | offsets[N+1] | pkS[E] u32 | packed[E] u32 |
    //      dlS[E] u8 | pad | emb16  (~28.5 MB) ----
    const int G = (N + SPAN - 1) / SPAN;
    const int M2 = G * NCHUNK;
    const int numB2 = (M2 + SB - 1) / SB;
    size_t intsA2 = (size_t)M2 + (size_t)(M2 + 1) + 2 * (size_t)numB2
                  + (size_t)(N + 1);
    size_t pkOff = intsA2 * sizeof(int);
    size_t dlOff = pkOff + (size_t)E * 2 * sizeof(unsigned int);
    size_t embOff2 = (dlOff + (size_t)E + 15) & ~(size_t)15;
    size_t neededA2 = embOff2 + (size_t)N * EMB_D * sizeof(__half);

    // ---- Tier A workspace (~21.7 MB) ----
    size_t intsA = (size_t)(2 * N + 1 + 2 * numB) + E;
    size_t ranksOff = intsA * sizeof(int);
    size_t embOffA = (ranksOff + (size_t)E * sizeof(unsigned short) + 15)
                     & ~(size_t)15;
    size_t neededA = embOffA + (size_t)N * EMB_D * sizeof(__half);

    // ---- Tier B (R11) workspace ----
    size_t intsB = (size_t)(9 * N + N + 1 + 2 * numB) + E;
    size_t embOffB = (intsB * sizeof(int) + 15) & ~(size_t)15;
    size_t neededB = embOffB + (size_t)N * EMB_D * sizeof(__half);

    if (ws_size >= neededA2 && G <= MAXG && numB2 <= 1024 && E < (1 << 28)) {
        int* cntT     = (int*)d_ws;              // G*NCHUNK
        int* scanT    = cntT + M2;               // G*NCHUNK+1
        int* partial  = scanT + M2 + 1;          // numB2
        int* blockoff = partial + numB2;         // numB2
        int* offsets  = blockoff + numB2;        // N+1
        unsigned int* pkS    = (unsigned int*)((char*)d_ws + pkOff);   // E
        unsigned int* packed = pkS + E;                                // E
        unsigned char* dlS   = (unsigned char*)((char*)d_ws + dlOff);  // E
        __half2* emb16 = (__half2*)((char*)d_ws + embOff2);

        const int chunk = (E + NCHUNK - 1) / NCHUNK;
        int n2 = N * (EMB_D / 2);

        a1_cast_hist<<<CAST_BLOCKS + NCHUNK, block, 0, stream>>>(
            (const float2*)emb, emb16, n2, dst, cntT, E, G, chunk);

        scan_reduceB<<<numB2, SB, 0, stream>>>(cntT, partial, M2);
        scan_partials<<<1, SB, 0, stream>>>(partial, blockoff, scanT, numB2, M2);
        scan_applyB<<<numB2, SB, 0, stream>>>(cntT, blockoff, scanT, M2);

        partition_scatter<<<NCHUNK, block, 0, stream>>>(src, dst, w, scanT,
                                                        pkS, dlS, E, G, chunk);
        group_csr<<<G, block, 0, stream>>>(pkS, dlS, scanT, packed, offsets,
                                           N, E);

        int gridN = (N + 3) / 4;
        gatherS_kernel<<<gridN, 256, 0, stream>>>((const uint2*)emb16, offsets,
                                                  packed, out, N);
    } else if (ws_size >= neededA && numB <= 1024) {
        int* counts   = (int*)d_ws;              // N
        int* offsets  = counts + N;              // N+1
        int* partial  = offsets + N + 1;
        int* blockoff = partial + numB;
        unsigned int* packed = (unsigned int*)(blockoff + numB);   // E
        unsigned short* ranks = (unsigned short*)((char*)d_ws + ranksOff);
        __half2* emb16 = (__half2*)((char*)d_ws + embOffA);

        hipMemsetAsync(counts, 0, (size_t)N * sizeof(int), stream);

        int n2 = N * (EMB_D / 2);
        p1_cast_hist_ranks<<<CAST_BLOCKS + 1024, block, 0, stream>>>(
            (const float2*)emb, emb16, n2, dst, counts, ranks, E);

        scan_reduceB<<<numB, SB, 0, stream>>>(counts, partial, N);
        scan_partials<<<1, SB, 0, stream>>>(partial, blockoff, offsets, numB, N);
        scan_applyB<<<numB, SB, 0, stream>>>(counts, blockoff, offsets, N);

        int span = (N + 7) / 8;
        bucketR_kernel<<<8 * 256, block, 0, stream>>>(src, dst, w, ranks,
                                                      offsets, packed, E, span, N);

        int gridN = (N + 3) / 4;
        gatherS_kernel<<<gridN, 256, 0, stream>>>((const uint2*)emb16, offsets,
                                                  packed, out, N);
    } else if (ws_size >= neededB && numB <= 1024) {
        int* counts8  = (int*)d_ws;
        int* cursors  = counts8 + (size_t)8 * N;
        int* offsets  = cursors + N;
        int* partial  = offsets + N + 1;
        int* blockoff = partial + numB;
        unsigned int* packed = (unsigned int*)(blockoff + numB);
        __half2* emb16 = (__half2*)((char*)d_ws + embOffB);

        hipMemsetAsync(counts8, 0, (size_t)8 * N * sizeof(int), stream);

        int n2 = N * (EMB_D / 2);
        fused_cast_hist<<<CAST_BLOCKS + 1024, block, 0, stream>>>(
            (const float2*)emb, emb16, n2, dst, counts8, E, N);
        scan_reduceF<<<numB, SB, 0, stream>>>(counts8, partial, N);
        scan_partials<<<1, SB, 0, stream>>>(partial, blockoff, offsets, numB, N);
        scan_applyF<<<numB, SB, 0, stream>>>(counts8, blockoff, offsets, cursors, N);

        int span = (N + 7) / 8;
        bucketS_kernel<<<8 * 256, block, 0, stream>>>(src, dst, w, cursors,
                                                      packed, E, span, N);
        int gridN = (N + 3) / 4;
        gatherS_kernel<<<gridN, 256, 0, stream>>>((const uint2*)emb16, offsets,
                                                  packed, out, N);
    } else {
        hipMemsetAsync(d_out, 0, (size_t)out_size * sizeof(float), stream);
        long long total = (long long)E * 16;
        int grid = (int)((total + block - 1) / block);
        lightgcn_scatter<<<grid, block, 0, stream>>>(emb, w, src, dst, out, E);
        int gridN = (N + 3) / 4;
        lightgcn_normalize<<<gridN, 256, 0, stream>>>(out, N);
    }
}

// Round 2
// 189.649 us; speedup vs baseline: 1.4255x; 1.1697x over previous
//
#include <hip/hip_runtime.h>
#include <hip/hip_fp16.h>

#define EMB_D 64
#define SB 1024     // scan block size
#define SPAN 128    // nodes per group (pow2: group = dst>>7, local = dst&127)
#define MAXG 1024   // max groups supported by LDS arrays
#define NCHUNK 256  // edge chunks (Tier A2 fallback)
#define NCHUNK2 512 // edge chunks (Tier A3: LDS-sorted partition)
#define CHMAX 4096  // max edges per chunk for LDS record buffer (32 KB)

// ===========================================================================
// Tier A3: ZERO global atomics + LDS-sorted partition (coalesced drain).
//   A1: fused fp16 cast + per-chunk group histogram (LDS atomics)
//   scan: 3-phase over [G][NCHUNK2] matrix -> per-(chunk,group) bases
//   PS : per-chunk LDS counting sort -> linear drain of 8B records into
//        group-contiguous streams (runs of ~7 records = coalesced-ish)
//   B  : per-group block: LDS node hist -> offsets[] + exact CSR placement
//   P3 : gatherS (quarter-wave, 2-deep pipeline, fused L2 norm) -- unchanged
// Tier A2: previous scattered-write partition (proven 222 us).
// Tier A: one-global-atomic-pass pipeline (proven 270 us).
// Tier B: R11 pipeline (proven 308 us). Tier C: atomic scatter.
// ===========================================================================

__device__ __forceinline__ float h15_to_float(unsigned int bits) {
    return __half2float(__ushort_as_half((unsigned short)bits));
}

#define CAST_BLOCKS 256

// --- A1: fused cast + chunked group histogram (no global atomics) ---------
// ncols = stride of the cnt matrix (NCHUNK or NCHUNK2)
__global__ void a1_cast_hist(const float2* __restrict__ embin,
                             __half2* __restrict__ emb16, int n2,
                             const int* __restrict__ dst,
                             int* __restrict__ cntT,   // [G][ncols]
                             int E, int G, int chunk, int ncols) {
    if (blockIdx.x < CAST_BLOCKS) {
        int i = blockIdx.x * blockDim.x + threadIdx.x;
        int st = CAST_BLOCKS * blockDim.x;
        for (; i < n2; i += st)
            emb16[i] = __float22half2_rn(embin[i]);
    } else {
        __shared__ int bins[MAXG];
        int hb = blockIdx.x - CAST_BLOCKS;
        for (int g = threadIdx.x; g < G; g += blockDim.x) bins[g] = 0;
        __syncthreads();
        int beg = hb * chunk;
        int end = min(beg + chunk, E);
        for (int i = beg + threadIdx.x; i < end; i += blockDim.x)
            atomicAdd(&bins[dst[i] >> 7], 1);
        __syncthreads();
        for (int g = threadIdx.x; g < G; g += blockDim.x)
            cntT[g * ncols + hb] = bins[g];
    }
}

// --- generic 3-phase exclusive scan ---------------------------------------
__global__ void scan_reduceB(const int* __restrict__ counts,
                             int* __restrict__ partial, int M) {
    __shared__ int wsum[16];
    const int tid = threadIdx.x, lane = tid & 63, wid = tid >> 6;
    int i = blockIdx.x * SB + tid;
    int v = (i < M) ? counts[i] : 0;
    #pragma unroll
    for (int off = 32; off > 0; off >>= 1)
        v += __shfl_xor(v, off, 64);
    if (lane == 0) wsum[wid] = v;
    __syncthreads();
    if (tid == 0) {
        int s = 0;
        #pragma unroll
        for (int k = 0; k < 16; ++k) s += wsum[k];
        partial[blockIdx.x] = s;
    }
}

__global__ void scan_partials(const int* __restrict__ partial,
                              int* __restrict__ blockoff,
                              int* __restrict__ offsets, int numB, int M) {
    __shared__ int wsum[16];
    __shared__ int wpre[16];
    const int tid = threadIdx.x, lane = tid & 63, wid = tid >> 6;
    int v = (tid < numB) ? partial[tid] : 0;
    int x = v;
    #pragma unroll
    for (int off = 1; off < 64; off <<= 1) {
        int t = __shfl_up(x, off, 64);
        if (lane >= off) x += t;
    }
    if (lane == 63) wsum[wid] = x;
    __syncthreads();
    if (wid == 0) {
        int s = (lane < 16) ? wsum[lane] : 0;
        #pragma unroll
        for (int off = 1; off < 16; off <<= 1) {
            int t = __shfl_up(s, off, 64);
            if (lane >= off) s += t;
        }
        if (lane < 16) wpre[lane] = s;
    }
    __syncthreads();
    int excl = ((wid > 0) ? wpre[wid - 1] : 0) + (x - v);
    if (tid < numB) blockoff[tid] = excl;
    if (tid == 0) offsets[M] = wpre[15];   // grand total = E
}

__global__ void scan_applyB(const int* __restrict__ counts,
                            const int* __restrict__ blockoff,
                            int* __restrict__ offsets, int M) {
    __shared__ int wsum[16];
    __shared__ int wpre[16];
    const int tid = threadIdx.x, lane = tid & 63, wid = tid >> 6;
    int i = blockIdx.x * SB + tid;
    int v = (i < M) ? counts[i] : 0;
    int x = v;
    #pragma unroll
    for (int off = 1; off < 64; off <<= 1) {
        int t = __shfl_up(x, off, 64);
        if (lane >= off) x += t;
    }
    if (lane == 63) wsum[wid] = x;
    __syncthreads();
    if (wid == 0) {
        int s = (lane < 16) ? wsum[lane] : 0;
        #pragma unroll
        for (int off = 1; off < 16; off <<= 1) {
            int t = __shfl_up(s, off, 64);
            if (lane >= off) s += t;
        }
        if (lane < 16) wpre[lane] = s;
    }
    __syncthreads();
    int excl = blockoff[blockIdx.x] + ((wid > 0) ? wpre[wid - 1] : 0) + (x - v);
    if (i < M) offsets[i] = excl;
}

// --- A3-PS: per-chunk LDS counting sort + linear coalesced drain ----------
// Record layout in LDS: .x = pk (src<<15 | w15), .y = dl | (g<<7).
// Drain strips g: global record = {pk, dl}.
__global__ __launch_bounds__(256) void partition_sort(
        const int* __restrict__ src,
        const int* __restrict__ dst,
        const float* __restrict__ w,
        const int* __restrict__ cntT,    // [G][NCHUNK2]
        const int* __restrict__ scanT,   // [G*NCHUNK2+1]
        uint2* __restrict__ stream8,     // [E]
        int E, int G, int chunk) {
    __shared__ uint2 recs[CHMAX];        // 32 KB
    __shared__ int cur[MAXG];            // local cursors (start at localbase)
    __shared__ int delta[MAXG];          // scanT base - localbase
    __shared__ int wtot[4];

    const int tid = threadIdx.x, lane = tid & 63, wv = tid >> 6;
    const int b = blockIdx.x;
    const int beg = b * chunk;
    const int end = min(beg + chunk, E);
    const int n = end - beg;

    // segment scan over per-group counts: thread t owns g in [t*K, t*K+K)
    const int K = (G + 255) >> 8;        // <= 4 (MAXG/256)
    int vals[4];
    int acc = 0;
    #pragma unroll
    for (int k = 0; k < 4; ++k) {
        int g = tid * K + k;
        int c = (k < K && g < G) ? cntT[g * NCHUNK2 + b] : 0;
        vals[k] = c;
        acc += c;
    }
    int x = acc;
    #pragma unroll
    for (int off = 1; off < 64; off <<= 1) {
        int t = __shfl_up(x, off, 64);
        if (lane >= off) x += t;
    }
    if (lane == 63) wtot[wv] = x;
    __syncthreads();
    int woff = 0;
    #pragma unroll
    for (int k2 = 0; k2 < 4; ++k2)
        woff += (k2 < wv) ? wtot[k2] : 0;
    int run = woff + x - acc;            // exclusive prefix (local base)
    #pragma unroll
    for (int k = 0; k < 4; ++k) {
        int g = tid * K + k;
        if (k < K && g < G) {
            cur[g] = run;
            delta[g] = scanT[g * NCHUNK2 + b] - run;
            run += vals[k];
        }
    }
    __syncthreads();

    // LDS scatter: group-sorted records
    for (int i = beg + tid; i < end; i += blockDim.x) {
        int d = dst[i];
        unsigned int wb = __half_as_ushort(__float2half_rn(w[i]));
        unsigned int pk = ((unsigned int)src[i] << 15) | (wb & 0x7FFFu);
        int g = d >> 7;
        int j = atomicAdd(&cur[g], 1);
        recs[j] = make_uint2(pk, (unsigned int)(d & (SPAN - 1)) |
                                 ((unsigned int)g << 7));
    }
    __syncthreads();

    // linear drain: consecutive j within a group-run -> consecutive global pos
    for (int j = tid; j < n; j += blockDim.x) {
        uint2 r = recs[j];
        int g = (int)(r.y >> 7);
        stream8[delta[g] + j] = make_uint2(r.x, r.y & (SPAN - 1u));
    }
}

// --- A3-B: per-group CSR finalize from uint2 stream -----------------------
__global__ void group_csr2(const uint2* __restrict__ stream8,
                           const int* __restrict__ scanT,
                           unsigned int* __restrict__ packed,
                           int* __restrict__ offsets, int N, int E) {
    __shared__ int hcnt[SPAN];
    __shared__ int cur[SPAN];
    __shared__ int wtot[4];
    int g = blockIdx.x;
    int tid = threadIdx.x;
    int base = scanT[g * NCHUNK2];
    int endE = scanT[(g + 1) * NCHUNK2];   // g == G-1 -> scanT[G*NCHUNK2] = E
    if (tid < SPAN) hcnt[tid] = 0;
    __syncthreads();
    for (int i = base + tid; i < endE; i += blockDim.x)
        atomicAdd(&hcnt[stream8[i].y], 1);
    __syncthreads();
    int v = (tid < SPAN) ? hcnt[tid] : 0;
    int lane = tid & 63, wv = tid >> 6;
    int x = v;
    #pragma unroll
    for (int off = 1; off < 64; off <<= 1) {
        int t = __shfl_up(x, off, 64);
        if (lane >= off) x += t;
    }
    if (lane == 63) wtot[wv] = x;
    __syncthreads();
    if (tid < SPAN) {
        int excl = x - v + ((wv == 1) ? wtot[0] : 0);
        cur[tid] = base + excl;
        int node = g * SPAN + tid;
        if (node < N) offsets[node] = base + excl;
    }
    if (g == 0 && tid == 0) offsets[N] = E;
    __syncthreads();
    for (int i = base + tid; i < endE; i += blockDim.x) {
        uint2 r = stream8[i];
        int slot = atomicAdd(&cur[r.y], 1);
        packed[slot] = r.x;
    }
}

// --- A2: scatter edges into group-contiguous streams (LDS cursors only) ---
__global__ void partition_scatter(const int* __restrict__ src,
                                  const int* __restrict__ dst,
                                  const float* __restrict__ w,
                                  const int* __restrict__ scanT,   // [G*NCHUNK+1]
                                  unsigned int* __restrict__ pkS,  // [E]
                                  unsigned char* __restrict__ dlS, // [E]
                                  int E, int G, int chunk) {
    __shared__ int cur[MAXG];
    int b = blockIdx.x;
    for (int g = threadIdx.x; g < G; g += blockDim.x)
        cur[g] = scanT[g * NCHUNK + b];
    __syncthreads();
    int beg = b * chunk;
    int end = min(beg + chunk, E);
    for (int i = beg + threadIdx.x; i < end; i += blockDim.x) {
        int d = dst[i];
        unsigned int wb = __half_as_ushort(__float2half_rn(w[i]));
        unsigned int pk = ((unsigned int)src[i] << 15) | (wb & 0x7FFFu);
        int pos = atomicAdd(&cur[d >> 7], 1);
        pkS[pos] = pk;
        dlS[pos] = (unsigned char)(d & (SPAN - 1));
    }
}

// --- A2-B: per-group CSR finalize (split pk/dl streams) -------------------
__global__ void group_csr(const unsigned int* __restrict__ pkS,
                          const unsigned char* __restrict__ dlS,
                          const int* __restrict__ scanT,
                          unsigned int* __restrict__ packed,
                          int* __restrict__ offsets, int N, int E) {
    __shared__ int hcnt[SPAN];
    __shared__ int cur[SPAN];
    __shared__ int wtot[4];
    int g = blockIdx.x;
    int tid = threadIdx.x;
    int base = scanT[g * NCHUNK];
    int endE = scanT[(g + 1) * NCHUNK];
    if (tid < SPAN) hcnt[tid] = 0;
    __syncthreads();
    for (int i = base + tid; i < endE; i += blockDim.x)
        atomicAdd(&hcnt[dlS[i]], 1);
    __syncthreads();
    int v = (tid < SPAN) ? hcnt[tid] : 0;
    int lane = tid & 63, wv = tid >> 6;
    int x = v;
    #pragma unroll
    for (int off = 1; off < 64; off <<= 1) {
        int t = __shfl_up(x, off, 64);
        if (lane >= off) x += t;
    }
    if (lane == 63) wtot[wv] = x;
    __syncthreads();
    if (tid < SPAN) {
        int excl = x - v + ((wv == 1) ? wtot[0] : 0);
        cur[tid] = base + excl;
        int node = g * SPAN + tid;
        if (node < N) offsets[node] = base + excl;
    }
    if (g == 0 && tid == 0) offsets[N] = E;
    __syncthreads();
    for (int i = base + tid; i < endE; i += blockDim.x) {
        unsigned int pk = pkS[i];
        int slot = atomicAdd(&cur[dlS[i]], 1);
        packed[slot] = pk;
    }
}

// --- P1 (old Tier A): fused cast + histogram-with-ranks -------------------
__global__ void p1_cast_hist_ranks(const float2* __restrict__ embin,
                                   __half2* __restrict__ emb16, int n2,
                                   const int* __restrict__ dst,
                                   int* __restrict__ counts,
                                   unsigned short* __restrict__ ranks,
                                   int E) {
    if (blockIdx.x < CAST_BLOCKS) {
        int i = blockIdx.x * blockDim.x + threadIdx.x;
        int st = CAST_BLOCKS * blockDim.x;
        for (; i < n2; i += st)
            emb16[i] = __float22half2_rn(embin[i]);
    } else {
        int i = (blockIdx.x - CAST_BLOCKS) * blockDim.x + threadIdx.x;
        int st = (gridDim.x - CAST_BLOCKS) * blockDim.x;
        for (; i < E; i += st)
            ranks[i] = (unsigned short)atomicAdd(&counts[dst[i]], 1);
    }
}

// --- P2 (old Tier A): atomic-free packed bucket ---------------------------
__global__ void bucketR_kernel(const int* __restrict__ src,
                               const int* __restrict__ dst,
                               const float* __restrict__ w,
                               const unsigned short* __restrict__ ranks,
                               const int* __restrict__ offsets,
                               unsigned int* __restrict__ packed,
                               int E, int span, int N) {
    int g = blockIdx.x & 7;
    int b = blockIdx.x >> 3;
    int lo = g * span;
    int hi = min(lo + span, N);
    int stride = (gridDim.x >> 3) * blockDim.x;
    for (int i = b * blockDim.x + threadIdx.x; i < E; i += stride) {
        int v = dst[i];
        if (v >= lo && v < hi) {
            unsigned int wb = __half_as_ushort(__float2half_rn(w[i]));
            packed[offsets[v] + (int)ranks[i]] =
                ((unsigned int)src[i] << 15) | (wb & 0x7FFFu);
        }
    }
}

// --- P3: fp16 gather, quarter-wave per edge, 2-deep pipeline --------------
__global__ __launch_bounds__(256) void gatherS_kernel(
        const uint2* __restrict__ emb16,       // row v = 16 x uint2 (128 B)
        const int* __restrict__ offsets,       // [N+1]
        const unsigned int* __restrict__ packed,
        float* __restrict__ out, int N) {
    int node = blockIdx.x * 4 + (threadIdx.x >> 6);
    int lane = threadIdx.x & 63;
    if (node >= N) return;
    int q  = lane >> 4;
    int ql = lane & 15;

    int beg = offsets[node];
    int end = offsets[node + 1];

    float a0 = 0.f, a1 = 0.f, a2 = 0.f, a3 = 0.f;

    int idx0 = beg + q;
    unsigned int pk0 = (idx0 < end) ? packed[idx0] : 0u;
    uint2 r0 = emb16[(size_t)(pk0 >> 15) * 16 + ql];

    for (int j = beg; j < end; j += 4) {
        int idx1 = idx0 + 4;
        unsigned int pk1 = (idx1 < end) ? packed[idx1] : 0u;
        uint2 r1 = emb16[(size_t)(pk1 >> 15) * 16 + ql];  // next in flight

        float wt = h15_to_float(pk0 & 0x7FFFu);
        float2 x01 = __half22float2(*reinterpret_cast<__half2*>(&r0.x));
        float2 x23 = __half22float2(*reinterpret_cast<__half2*>(&r0.y));
        a0 = fmaf(x01.x, wt, a0);
        a1 = fmaf(x01.y, wt, a1);
        a2 = fmaf(x23.x, wt, a2);
        a3 = fmaf(x23.y, wt, a3);

        pk0 = pk1; r0 = r1; idx0 = idx1;
    }

    a0 += __shfl_xor(a0, 16, 64); a0 += __shfl_xor(a0, 32, 64);
    a1 += __shfl_xor(a1, 16, 64); a1 += __shfl_xor(a1, 32, 64);
    a2 += __shfl_xor(a2, 16, 64); a2 += __shfl_xor(a2, 32, 64);
    a3 += __shfl_xor(a3, 16, 64); a3 += __shfl_xor(a3, 32, 64);

    float ss = a0 * a0 + a1 * a1 + a2 * a2 + a3 * a3;
    #pragma unroll
    for (int off = 8; off > 0; off >>= 1)
        ss += __shfl_xor(ss, off, 64);
    float scale = 1.0f / fmaxf(sqrtf(ss), 1e-12f);

    if (q == 0) {
        float4 o = make_float4(a0 * scale, a1 * scale, a2 * scale, a3 * scale);
        reinterpret_cast<float4*>(out + (size_t)node * EMB_D)[ql] = o;
    }
}

// ===========================================================================
// Tier B: R11 pipeline (proven 308 us).
// ===========================================================================
__global__ void fused_cast_hist(const float2* __restrict__ embin,
                                __half2* __restrict__ emb16, int n2,
                                const int* __restrict__ dst,
                                int* __restrict__ counts8, int E, int N) {
    if (blockIdx.x < CAST_BLOCKS) {
        int i = blockIdx.x * blockDim.x + threadIdx.x;
        int st = CAST_BLOCKS * blockDim.x;
        for (; i < n2; i += st)
            emb16[i] = __float22half2_rn(embin[i]);
    } else {
        int* mycounts = counts8 + (size_t)(blockIdx.x & 7) * N;
        int i = (blockIdx.x - CAST_BLOCKS) * blockDim.x + threadIdx.x;
        int st = (gridDim.x - CAST_BLOCKS) * blockDim.x;
        for (; i < E; i += st)
            atomicAdd(&mycounts[dst[i]], 1);
    }
}

__device__ __forceinline__ int fold8(const int* counts8, int i, int N) {
    int v = 0;
    #pragma unroll
    for (int g = 0; g < 8; ++g) v += counts8[(size_t)g * N + i];
    return v;
}

__global__ void scan_reduceF(const int* __restrict__ counts8,
                             int* __restrict__ partial, int N) {
    __shared__ int wsum[16];
    const int tid = threadIdx.x, lane = tid & 63, wid = tid >> 6;
    int i = blockIdx.x * SB + tid;
    int v = (i < N) ? fold8(counts8, i, N) : 0;
    #pragma unroll
    for (int off = 32; off > 0; off >>= 1)
        v += __shfl_xor(v, off, 64);
    if (lane == 0) wsum[wid] = v;
    __syncthreads();
    if (tid == 0) {
        int s = 0;
        #pragma unroll
        for (int k = 0; k < 16; ++k) s += wsum[k];
        partial[blockIdx.x] = s;
    }
}

__global__ void scan_applyF(const int* __restrict__ counts8,
                            const int* __restrict__ blockoff,
                            int* __restrict__ offsets,
                            int* __restrict__ cursors, int N) {
    __shared__ int wsum[16];
    __shared__ int wpre[16];
    const int tid = threadIdx.x, lane = tid & 63, wid = tid >> 6;
    int i = blockIdx.x * SB + tid;
    int v = (i < N) ? fold8(counts8, i, N) : 0;
    int x = v;
    #pragma unroll
    for (int off = 1; off < 64; off <<= 1) {
        int t = __shfl_up(x, off, 64);
        if (lane >= off) x += t;
    }
    if (lane == 63) wsum[wid] = x;
    __syncthreads();
    if (wid == 0) {
        int s = (lane < 16) ? wsum[lane] : 0;
        #pragma unroll
        for (int off = 1; off < 16; off <<= 1) {
            int t = __shfl_up(s, off, 64);
            if (lane >= off) s += t;
        }
        if (lane < 16) wpre[lane] = s;
    }
    __syncthreads();
    int excl = blockoff[blockIdx.x] + ((wid > 0) ? wpre[wid - 1] : 0) + (x - v);
    if (i < N) { offsets[i] = excl; cursors[i] = excl; }
}

__global__ void bucketS_kernel(const int* __restrict__ src,
                               const int* __restrict__ dst,
                               const float* __restrict__ w,
                               int* __restrict__ cursors,
                               unsigned int* __restrict__ packed,
                               int E, int span, int N) {
    int g = blockIdx.x & 7;
    int b = blockIdx.x >> 3;
    int lo = g * span;
    int hi = min(lo + span, N);
    int stride = (gridDim.x >> 3) * blockDim.x;
    for (int i = b * blockDim.x + threadIdx.x; i < E; i += stride) {
        int v = dst[i];
        if (v >= lo && v < hi) {
            int slot = atomicAdd(&cursors[v], 1);
            unsigned int wb = __half_as_ushort(__float2half_rn(w[i]));
            packed[slot] = ((unsigned int)src[i] << 15) | (wb & 0x7FFFu);
        }
    }
}

// ===========================================================================
// Tier C: atomic scatter fallback.
// ===========================================================================
__global__ void lightgcn_scatter(const float* __restrict__ emb,
                                 const float* __restrict__ w,
                                 const int* __restrict__ src,
                                 const int* __restrict__ dst,
                                 float* __restrict__ h, int E) {
    long long t = (long long)blockIdx.x * blockDim.x + threadIdx.x;
    int e = (int)(t >> 4);
    int d = (int)(t & 15) << 2;
    if (e >= E) return;
    int s = src[e]; int v = dst[e]; float wt = w[e];
    const float4 m = *reinterpret_cast<const float4*>(emb + (size_t)s * EMB_D + d);
    float* o = h + (size_t)v * EMB_D + d;
    unsafeAtomicAdd(o + 0, m.x * wt);
    unsafeAtomicAdd(o + 1, m.y * wt);
    unsafeAtomicAdd(o + 2, m.z * wt);
    unsafeAtomicAdd(o + 3, m.w * wt);
}

__global__ void lightgcn_normalize(float* __restrict__ h, int N) {
    int row = blockIdx.x * (blockDim.x >> 6) + (threadIdx.x >> 6);
    int lane = threadIdx.x & 63;
    if (row >= N) return;
    float x = h[(size_t)row * EMB_D + lane];
    float ss = x * x;
    #pragma unroll
    for (int off = 32; off > 0; off >>= 1)
        ss += __shfl_xor(ss, off, 64);
    h[(size_t)row * EMB_D + lane] = x / fmaxf(sqrtf(ss), 1e-12f);
}

extern "C" void kernel_launch(void* const* d_in, const int* in_sizes, int n_in,
                              void* d_out, int out_size, void* d_ws, size_t ws_size,
                              hipStream_t stream) {
    const float* emb = (const float*)d_in[0];   // [N, 64] fp32
    const float* w   = (const float*)d_in[1];   // [E] fp32
    const int*   src = (const int*)d_in[2];     // [E] int32
    const int*   dst = (const int*)d_in[3];     // [E] int32
    float* out = (float*)d_out;

    const int N = in_sizes[0] / EMB_D;
    const int E = in_sizes[1];
    const int block = 256;
    const int numB = (N + SB - 1) / SB;
    const int G = (N + SPAN - 1) / SPAN;

    // ---- Tier A3 workspace: cntT[G*NCHUNK2] | scanT[G*NCHUNK2+1] | partial |
    //      blockoff | offsets[N+1] | pad | stream8[E] uint2 | packed[E] u32 |
    //      pad | emb16  (~35.7 MB) ----
    const int M3 = G * NCHUNK2;
    const int numB3 = (M3 + SB - 1) / SB;
    const int chunk3 = (E + NCHUNK2 - 1) / NCHUNK2;
    size_t intsA3 = (size_t)M3 + (size_t)(M3 + 1) + 2 * (size_t)numB3
                  + (size_t)(N + 1);
    size_t strOff = (intsA3 * sizeof(int) + 15) & ~(size_t)15;
    size_t pkdOff = strOff + (size_t)E * sizeof(uint2);
    size_t embOff3 = (pkdOff + (size_t)E * sizeof(unsigned int) + 15)
                     & ~(size_t)15;
    size_t neededA3 = embOff3 + (size_t)N * EMB_D * sizeof(__half);

    // ---- Tier A2 workspace (~28.5 MB) ----
    const int M2 = G * NCHUNK;
    const int numB2 = (M2 + SB - 1) / SB;
    size_t intsA2 = (size_t)M2 + (size_t)(M2 + 1) + 2 * (size_t)numB2
                  + (size_t)(N + 1);
    size_t pkOff = intsA2 * sizeof(int);
    size_t dlOff = pkOff + (size_t)E * 2 * sizeof(unsigned int);
    size_t embOff2 = (dlOff + (size_t)E + 15) & ~(size_t)15;
    size_t neededA2 = embOff2 + (size_t)N * EMB_D * sizeof(__half);

    // ---- Tier A workspace (~21.7 MB) ----
    size_t intsA = (size_t)(2 * N + 1 + 2 * numB) + E;
    size_t ranksOff = intsA * sizeof(int);
    size_t embOffA = (ranksOff + (size_t)E * sizeof(unsigned short) + 15)
                     & ~(size_t)15;
    size_t neededA = embOffA + (size_t)N * EMB_D * sizeof(__half);

    // ---- Tier B (R11) workspace ----
    size_t intsB = (size_t)(9 * N + N + 1 + 2 * numB) + E;
    size_t embOffB = (intsB * sizeof(int) + 15) & ~(size_t)15;
    size_t neededB = embOffB + (size_t)N * EMB_D * sizeof(__half);

    if (ws_size >= neededA3 && G <= MAXG && numB3 <= 1024 &&
        chunk3 <= CHMAX && E < (1 << 28)) {
        int* cntT     = (int*)d_ws;              // G*NCHUNK2
        int* scanT    = cntT + M3;               // G*NCHUNK2+1
        int* partial  = scanT + M3 + 1;          // numB3
        int* blockoff = partial + numB3;         // numB3
        int* offsets  = blockoff + numB3;        // N+1
        uint2* stream8 = (uint2*)((char*)d_ws + strOff);                // E
        unsigned int* packed = (unsigned int*)((char*)d_ws + pkdOff);   // E
        __half2* emb16 = (__half2*)((char*)d_ws + embOff3);

        int n2 = N * (EMB_D / 2);

        a1_cast_hist<<<CAST_BLOCKS + NCHUNK2, block, 0, stream>>>(
            (const float2*)emb, emb16, n2, dst, cntT, E, G, chunk3, NCHUNK2);

        scan_reduceB<<<numB3, SB, 0, stream>>>(cntT, partial, M3);
        scan_partials<<<1, SB, 0, stream>>>(partial, blockoff, scanT, numB3, M3);
        scan_applyB<<<numB3, SB, 0, stream>>>(cntT, blockoff, scanT, M3);

        partition_sort<<<NCHUNK2, block, 0, stream>>>(src, dst, w, cntT, scanT,
                                                      stream8, E, G, chunk3);
        group_csr2<<<G, block, 0, stream>>>(stream8, scanT, packed, offsets,
                                            N, E);

        int gridN = (N + 3) / 4;
        gatherS_kernel<<<gridN, 256, 0, stream>>>((const uint2*)emb16, offsets,
                                                  packed, out, N);
    } else if (ws_size >= neededA2 && G <= MAXG && numB2 <= 1024 &&
               E < (1 << 28)) {
        int* cntT     = (int*)d_ws;              // G*NCHUNK
        int* scanT    = cntT + M2;               // G*NCHUNK+1
        int* partial  = scanT + M2 + 1;          // numB2
        int* blockoff = partial + numB2;         // numB2
        int* offsets  = blockoff + numB2;        // N+1
        unsigned int* pkS    = (unsigned int*)((char*)d_ws + pkOff);   // E
        unsigned int* packed = pkS + E;                                // E
        unsigned char* dlS   = (unsigned char*)((char*)d_ws + dlOff);  // E
        __half2* emb16 = (__half2*)((char*)d_ws + embOff2);

        const int chunk = (E + NCHUNK - 1) / NCHUNK;
        int n2 = N * (EMB_D / 2);

        a1_cast_hist<<<CAST_BLOCKS + NCHUNK, block, 0, stream>>>(
            (const float2*)emb, emb16, n2, dst, cntT, E, G, chunk, NCHUNK);

        scan_reduceB<<<numB2, SB, 0, stream>>>(cntT, partial, M2);
        scan_partials<<<1, SB, 0, stream>>>(partial, blockoff, scanT, numB2, M2);
        scan_applyB<<<numB2, SB, 0, stream>>>(cntT, blockoff, scanT, M2);

        partition_scatter<<<NCHUNK, block, 0, stream>>>(src, dst, w, scanT,
                                                        pkS, dlS, E, G, chunk);
        group_csr<<<G, block, 0, stream>>>(pkS, dlS, scanT, packed, offsets,
                                           N, E);

        int gridN = (N + 3) / 4;
        gatherS_kernel<<<gridN, 256, 0, stream>>>((const uint2*)emb16, offsets,
                                                  packed, out, N);
    } else if (ws_size >= neededA && numB <= 1024) {
        int* counts   = (int*)d_ws;              // N
        int* offsets  = counts + N;              // N+1
        int* partial  = offsets + N + 1;
        int* blockoff = partial + numB;
        unsigned int* packed = (unsigned int*)(blockoff + numB);   // E
        unsigned short* ranks = (unsigned short*)((char*)d_ws + ranksOff);
        __half2* emb16 = (__half2*)((char*)d_ws + embOffA);

        hipMemsetAsync(counts, 0, (size_t)N * sizeof(int), stream);

        int n2 = N * (EMB_D / 2);
        p1_cast_hist_ranks<<<CAST_BLOCKS + 1024, block, 0, stream>>>(
            (const float2*)emb, emb16, n2, dst, counts, ranks, E);

        scan_reduceB<<<numB, SB, 0, stream>>>(counts, partial, N);
        scan_partials<<<1, SB, 0, stream>>>(partial, blockoff, offsets, numB, N);
        scan_applyB<<<numB, SB, 0, stream>>>(counts, blockoff, offsets, N);

        int span = (N + 7) / 8;
        bucketR_kernel<<<8 * 256, block, 0, stream>>>(src, dst, w, ranks,
                                                      offsets, packed, E, span, N);

        int gridN = (N + 3) / 4;
        gatherS_kernel<<<gridN, 256, 0, stream>>>((const uint2*)emb16, offsets,
                                                  packed, out, N);
    } else if (ws_size >= neededB && numB <= 1024) {
        int* counts8  = (int*)d_ws;
        int* cursors  = counts8 + (size_t)8 * N;
        int* offsets  = cursors + N;
        int* partial  = offsets + N + 1;
        int* blockoff = partial + numB;
        unsigned int* packed = (unsigned int*)(blockoff + numB);
        __half2* emb16 = (__half2*)((char*)d_ws + embOffB);

        hipMemsetAsync(counts8, 0, (size_t)8 * N * sizeof(int), stream);

        int n2 = N * (EMB_D / 2);
        fused_cast_hist<<<CAST_BLOCKS + 1024, block, 0, stream>>>(
            (const float2*)emb, emb16, n2, dst, counts8, E, N);
        scan_reduceF<<<numB, SB, 0, stream>>>(counts8, partial, N);
        scan_partials<<<1, SB, 0, stream>>>(partial, blockoff, offsets, numB, N);
        scan_applyF<<<numB, SB, 0, stream>>>(counts8, blockoff, offsets, cursors, N);

        int span = (N + 7) / 8;
        bucketS_kernel<<<8 * 256, block, 0, stream>>>(src, dst, w, cursors,
                                                      packed, E, span, N);
        int gridN = (N + 3) / 4;
        gatherS_kernel<<<gridN, 256, 0, stream>>>((const uint2*)emb16, offsets,
                                                  packed, out, N);
    } else {
        hipMemsetAsync(d_out, 0, (size_t)out_size * sizeof(float), stream);
        long long total = (long long)E * 16;
        int grid = (int)((total + block - 1) / block);
        lightgcn_scatter<<<grid, block, 0, stream>>>(emb, w, src, dst, out, E);
        int gridN = (N + 3) / 4;
        lightgcn_normalize<<<gridN, 256, 0, stream>>>(out, N);
    }
}